// Round 2
// baseline (452.750 us; speedup 1.0000x reference)
//
#include <hip/hip_runtime.h>

typedef __bf16 bf16;
typedef bf16 bf16x8 __attribute__((ext_vector_type(8)));
typedef bf16 bf16x4 __attribute__((ext_vector_type(4)));
typedef float f32x4 __attribute__((ext_vector_type(4)));

static constexpr int SEQ = 4096;
static constexpr int HID = 1024;
static constexpr int NHD = 16;
static constexpr int HDM = 64;

#define MFMA16(a, b, c) __builtin_amdgcn_mfma_f32_16x16x32_bf16((a), (b), (c), 0, 0, 0)

// Async global->LDS, 16B per lane. LDS dest is wave-uniform base + lane*16;
// global source address is per-lane (guide §5).
__device__ __forceinline__ void async_copy16(const bf16* g, bf16* lds) {
  __builtin_amdgcn_global_load_lds(
      (const __attribute__((address_space(1))) void*)g,
      (__attribute__((address_space(3))) void*)lds, 16, 0, 0);
}

// ---------------------------------------------------------------------------
// Kernel 0: cast fp32 -> bf16. Folds the 1/sqrt(64)=0.125 attention scale into
// the q-rows (rows [0,1024)) of W_qkv (exact power of two, no rounding cost).
// ---------------------------------------------------------------------------
__global__ __launch_bounds__(256) void cast_inputs(
    const float* __restrict__ x, const float* __restrict__ wqkv,
    const float* __restrict__ wout, bf16* __restrict__ xb,
    bf16* __restrict__ wqkvb, bf16* __restrict__ woutb) {
  const int NX = SEQ * HID;        // 4M
  const int NW = 3 * HID * HID;    // 3M
  const int NO = HID * HID;        // 1M
  const int tot4 = (NX + NW + NO) >> 2;
  for (int i4 = blockIdx.x * blockDim.x + threadIdx.x; i4 < tot4;
       i4 += gridDim.x * blockDim.x) {
    const int i = i4 << 2;
    const float* src;
    bf16* dst;
    float scale = 1.0f;
    int off;
    if (i < NX) {
      src = x; dst = xb; off = i;
    } else if (i < NX + NW) {
      off = i - NX; src = wqkv; dst = wqkvb;
      if (off < HID * HID) scale = 0.125f;  // q-rows
    } else {
      off = i - NX - NW; src = wout; dst = woutb;
    }
    f32x4 v = *reinterpret_cast<const f32x4*>(src + off);
    bf16x4 o;
#pragma unroll
    for (int j = 0; j < 4; ++j) o[j] = (bf16)(v[j] * scale);
    *reinterpret_cast<bf16x4*>(dst + off) = o;
  }
}

// ---------------------------------------------------------------------------
// GEMM C[M,N] = A[M,K] * B[N,K]^T, bf16 inputs, fp32 accum.
// 128x128 tile, BK=64, 4 waves (each 64x64 = 4x4 frags of 16x16x32 MFMA).
// EPI=0: fp32 row-major C.  EPI=1: scatter bf16 q[h][s][d] / k[h][s][d] /
// vt[h][d][s] (v pre-transposed for attention's B-operand reads).
// ---------------------------------------------------------------------------
template <int EPI>
__global__ __launch_bounds__(256) void gemm_bt(
    const bf16* __restrict__ A, const bf16* __restrict__ B,
    float* __restrict__ C, bf16* __restrict__ Qo, bf16* __restrict__ Ko,
    bf16* __restrict__ VTo, int M, int N, int K) {
  __shared__ __align__(16) bf16 lds_a[128 * 64];
  __shared__ __align__(16) bf16 lds_b[128 * 64];
  const int tid = threadIdx.x;
  const int lane = tid & 63;
  const int wv = tid >> 6;
  const int wr = wv >> 1, wc = wv & 1;
  const int rsel = lane & 15, hi = lane >> 4;
  const int m0 = blockIdx.y * 128;
  const int n0 = blockIdx.x * 128;
  f32x4 acc[4][4] = {};
  const int nk = K >> 6;
  for (int kt = 0; kt < nk; ++kt) {
    const int k0 = kt << 6;
    // stage A,B tiles: 16KB each = 16 wave-calls of 1KB; 4 per wave.
#pragma unroll
    for (int j = 0; j < 4; ++j) {
      const int cc = (wv * 4 + j) * 64;  // wave-uniform chunk base
      const int c = cc + lane;           // per-lane chunk in [0,1024)
      const int row = c >> 3, kc = (c & 7) << 3;
      async_copy16(A + (size_t)(m0 + row) * K + k0 + kc, lds_a + cc * 8);
      async_copy16(B + (size_t)(n0 + row) * K + k0 + kc, lds_b + cc * 8);
    }
    __syncthreads();  // drains vmcnt: staged data visible
#pragma unroll
    for (int kk = 0; kk < 2; ++kk) {
      const int kof = kk * 32 + hi * 8;
      bf16x8 af[4], bfr[4];
#pragma unroll
      for (int mi = 0; mi < 4; ++mi)
        af[mi] = *reinterpret_cast<const bf16x8*>(
            &lds_a[(wr * 64 + mi * 16 + rsel) * 64 + kof]);
#pragma unroll
      for (int ni = 0; ni < 4; ++ni)
        bfr[ni] = *reinterpret_cast<const bf16x8*>(
            &lds_b[(wc * 64 + ni * 16 + rsel) * 64 + kof]);
#pragma unroll
      for (int mi = 0; mi < 4; ++mi)
#pragma unroll
        for (int ni = 0; ni < 4; ++ni)
          acc[mi][ni] = MFMA16(af[mi], bfr[ni], acc[mi][ni]);
    }
    __syncthreads();  // all reads done before next stage overwrites
  }
  // Epilogue. D layout: row=(lane>>4)*4+i, col=lane&15 (verified m89/m91).
  if constexpr (EPI == 0) {
#pragma unroll
    for (int mi = 0; mi < 4; ++mi)
#pragma unroll
      for (int ni = 0; ni < 4; ++ni) {
        const int r0 = m0 + wr * 64 + mi * 16 + hi * 4;
        const int col = n0 + wc * 64 + ni * 16 + rsel;
#pragma unroll
        for (int i = 0; i < 4; ++i)
          C[(size_t)(r0 + i) * N + col] = acc[mi][ni][i];
      }
  } else {
#pragma unroll
    for (int mi = 0; mi < 4; ++mi)
#pragma unroll
      for (int ni = 0; ni < 4; ++ni) {
        const int r0 = m0 + wr * 64 + mi * 16 + hi * 4;
        const int n = n0 + wc * 64 + ni * 16 + rsel;
        const int qi = n >> 10;
        const int h = (n >> 6) & 15;
        const int d = n & 63;
#pragma unroll
        for (int i = 0; i < 4; ++i) {
          const bf16 val = (bf16)acc[mi][ni][i];
          const int s = r0 + i;
          if (qi == 0)
            Qo[((size_t)h * SEQ + s) * HDM + d] = val;
          else if (qi == 1)
            Ko[((size_t)h * SEQ + s) * HDM + d] = val;
          else
            VTo[((size_t)h * HDM + d) * SEQ + s] = val;
        }
      }
  }
}

// ---------------------------------------------------------------------------
// Flash attention fwd. Grid (SEQ/128, NHD). 4 waves x 32 q-rows each.
// Q pre-scaled by 1/sqrt(d) (folded into W_qkv). KV tiles of 64 staged via
// global_load_lds (K natural [t][d]; V from pre-transposed vt[h][d][s]).
// Online softmax; P transposed via per-wave private LDS for the PV A-operand.
// ---------------------------------------------------------------------------
__global__ __launch_bounds__(256) void attn_fwd(
    const bf16* __restrict__ Q, const bf16* __restrict__ K,
    const bf16* __restrict__ VT, bf16* __restrict__ O) {
  __shared__ __align__(16) bf16 lds_k[64 * 64];
  __shared__ __align__(16) bf16 lds_vt[64 * 64];
  __shared__ __align__(16) bf16 lds_p[4 * 32 * 64];
  const int tid = threadIdx.x, lane = tid & 63, wv = tid >> 6;
  const int rsel = lane & 15, hi = lane >> 4;
  const int h = blockIdx.y;
  const int s0 = blockIdx.x * 128 + wv * 32;  // this wave's first q-row
  const bf16* qh = Q + (size_t)h * SEQ * HDM;
  const bf16* kh = K + (size_t)h * SEQ * HDM;
  const bf16* vh = VT + (size_t)h * HDM * SEQ;
  bf16* my_p = lds_p + wv * 32 * 64;

  // Q fragments live in registers for the whole kernel (16 VGPRs).
  bf16x8 qf[2][2];
#pragma unroll
  for (int mi = 0; mi < 2; ++mi)
#pragma unroll
    for (int kk = 0; kk < 2; ++kk)
      qf[mi][kk] = *reinterpret_cast<const bf16x8*>(
          qh + (size_t)(s0 + mi * 16 + rsel) * HDM + kk * 32 + hi * 8);

  f32x4 ao[2][4] = {};
  float mrow[2][4], lrow[2][4];
#pragma unroll
  for (int mi = 0; mi < 2; ++mi)
#pragma unroll
    for (int i = 0; i < 4; ++i) {
      mrow[mi][i] = -1e30f;
      lrow[mi][i] = 0.0f;
    }

  for (int t0 = 0; t0 < SEQ; t0 += 64) {
    // stage K tile [t][d] (contiguous 8KB) + V tile [d][t] (strided source).
#pragma unroll
    for (int j = 0; j < 2; ++j) {
      const int cc = (wv * 2 + j) * 64;
      const int c = cc + lane;  // chunk in [0,512)
      async_copy16(kh + (size_t)t0 * HDM + c * 8, lds_k + cc * 8);
      async_copy16(vh + (size_t)(c >> 3) * SEQ + t0 + (c & 7) * 8,
                   lds_vt + cc * 8);
    }
    __syncthreads();  // vmcnt drained: tiles visible

    // QK^T: scores[32 q][64 t]
    f32x4 sc[2][4] = {};
#pragma unroll
    for (int kk = 0; kk < 2; ++kk) {
      const int kof = kk * 32 + hi * 8;
      bf16x8 bk[4];
#pragma unroll
      for (int ni = 0; ni < 4; ++ni)
        bk[ni] = *reinterpret_cast<const bf16x8*>(
            &lds_k[(ni * 16 + rsel) * 64 + kof]);
#pragma unroll
      for (int mi = 0; mi < 2; ++mi)
#pragma unroll
        for (int ni = 0; ni < 4; ++ni)
          sc[mi][ni] = MFMA16(qf[mi][kk], bk[ni], sc[mi][ni]);
    }

    // online softmax: row r = mi*16 + hi*4 + i lives in the 16 lanes of group
    // `hi`; reduce across them with xor-shuffles (masks < 16 stay in group).
#pragma unroll
    for (int mi = 0; mi < 2; ++mi)
#pragma unroll
      for (int i = 0; i < 4; ++i) {
        float mloc = fmaxf(fmaxf(sc[mi][0][i], sc[mi][1][i]),
                           fmaxf(sc[mi][2][i], sc[mi][3][i]));
#pragma unroll
        for (int msk = 1; msk <= 8; msk <<= 1)
          mloc = fmaxf(mloc, __shfl_xor(mloc, msk, 64));
        const float mnew = fmaxf(mrow[mi][i], mloc);
        const float scal = __expf(mrow[mi][i] - mnew);
        mrow[mi][i] = mnew;
        float psum = 0.0f;
#pragma unroll
        for (int ni = 0; ni < 4; ++ni) {
          const float p = __expf(sc[mi][ni][i] - mnew);
          sc[mi][ni][i] = p;
          psum += p;
        }
#pragma unroll
        for (int msk = 1; msk <= 8; msk <<= 1)
          psum += __shfl_xor(psum, msk, 64);
        lrow[mi][i] = lrow[mi][i] * scal + psum;
#pragma unroll
        for (int ni = 0; ni < 4; ++ni) ao[mi][ni][i] *= scal;
      }

    // P -> per-wave LDS (transpose from C/D layout to A-frag layout)
#pragma unroll
    for (int mi = 0; mi < 2; ++mi)
#pragma unroll
      for (int ni = 0; ni < 4; ++ni)
#pragma unroll
        for (int i = 0; i < 4; ++i)
          my_p[(mi * 16 + hi * 4 + i) * 64 + ni * 16 + rsel] =
              (bf16)sc[mi][ni][i];
    asm volatile("s_waitcnt lgkmcnt(0)" ::: "memory");

    // PV: out[32 q][64 d] += P[32 q][64 t] * V[64 t][64 d]
#pragma unroll
    for (int kk = 0; kk < 2; ++kk) {
      const int kof = kk * 32 + hi * 8;
      bf16x8 ap[2], bv[4];
#pragma unroll
      for (int mi = 0; mi < 2; ++mi)
        ap[mi] = *reinterpret_cast<const bf16x8*>(
            &my_p[(mi * 16 + rsel) * 64 + kof]);
#pragma unroll
      for (int ni = 0; ni < 4; ++ni)
        bv[ni] = *reinterpret_cast<const bf16x8*>(
            &lds_vt[(ni * 16 + rsel) * 64 + kof]);
#pragma unroll
      for (int mi = 0; mi < 2; ++mi)
#pragma unroll
        for (int ni = 0; ni < 4; ++ni)
          ao[mi][ni] = MFMA16(ap[mi], bv[ni], ao[mi][ni]);
    }
    __syncthreads();  // K/V tile reads done before next stage overwrites
  }

  // epilogue: O[s][h*64+d] = ao / l
#pragma unroll
  for (int mi = 0; mi < 2; ++mi)
#pragma unroll
    for (int i = 0; i < 4; ++i) {
      const float inv = 1.0f / lrow[mi][i];
      const int s = s0 + mi * 16 + hi * 4 + i;
#pragma unroll
      for (int ni = 0; ni < 4; ++ni)
        O[(size_t)s * HID + h * HDM + ni * 16 + rsel] =
            (bf16)(ao[mi][ni][i] * inv);
    }
}

// ---------------------------------------------------------------------------
// Workspace packing (40 MB total; aob reuses xb's slot — xb is dead after the
// QKV GEMM, and attention only reads q/k/vt):
//   [ 0, 8)  xb   [4096][1024] bf16   -> later aob [4096][1024] bf16
//   [ 8,14)  wqkvb[3072][1024] bf16
//   [14,16)  woutb[1024][1024] bf16
//   [16,24)  qb   [16][4096][64] bf16
//   [24,32)  kb   [16][4096][64] bf16
//   [32,40)  vtb  [16][64][4096] bf16
// ---------------------------------------------------------------------------
extern "C" void kernel_launch(void* const* d_in, const int* in_sizes, int n_in,
                              void* d_out, int out_size, void* d_ws,
                              size_t ws_size, hipStream_t stream) {
  const float* x = (const float*)d_in[0];
  const float* wqkv = (const float*)d_in[1];
  const float* wout = (const float*)d_in[2];
  float* out = (float*)d_out;
  char* ws = (char*)d_ws;
  const size_t MB = 1024 * 1024;
  bf16* xb = (bf16*)(ws);
  bf16* wqkvb = (bf16*)(ws + 8 * MB);
  bf16* woutb = (bf16*)(ws + 14 * MB);
  bf16* qb = (bf16*)(ws + 16 * MB);
  bf16* kb = (bf16*)(ws + 24 * MB);
  bf16* vtb = (bf16*)(ws + 32 * MB);
  bf16* aob = (bf16*)(ws);  // aliases xb (dead by then)

  cast_inputs<<<2048, 256, 0, stream>>>(x, wqkv, wout, xb, wqkvb, woutb);
  gemm_bt<1><<<dim3(3 * HID / 128, SEQ / 128), 256, 0, stream>>>(
      xb, wqkvb, nullptr, qb, kb, vtb, SEQ, 3 * HID, HID);
  attn_fwd<<<dim3(SEQ / 128, NHD), 256, 0, stream>>>(qb, kb, vtb, aob);
  gemm_bt<0><<<dim3(HID / 128, SEQ / 128), 256, 0, stream>>>(
      aob, woutb, out, nullptr, nullptr, nullptr, SEQ, HID, HID);
}

// Round 4
// 408.963 us; speedup vs baseline: 1.1071x; 1.1071x over previous
//
#include <hip/hip_runtime.h>

typedef __bf16 bf16;
typedef bf16 bf16x8 __attribute__((ext_vector_type(8)));
typedef bf16 bf16x4 __attribute__((ext_vector_type(4)));
typedef float f32x4 __attribute__((ext_vector_type(4)));
typedef float f32x16 __attribute__((ext_vector_type(16)));

static constexpr int SEQ = 4096;
static constexpr int HID = 1024;
static constexpr int NHD = 16;
static constexpr int HDM = 64;

#define MFMA16(a, b, c) __builtin_amdgcn_mfma_f32_16x16x32_bf16((a), (b), (c), 0, 0, 0)
#define MFMA32(a, b, c) __builtin_amdgcn_mfma_f32_32x32x16_bf16((a), (b), (c), 0, 0, 0)

__device__ __forceinline__ void async_copy16(const bf16* g, bf16* lds) {
  __builtin_amdgcn_global_load_lds(
      (const __attribute__((address_space(1))) void*)g,
      (__attribute__((address_space(3))) void*)lds, 16, 0, 0);
}

__device__ __forceinline__ float fexp2(float x) {
#if __has_builtin(__builtin_amdgcn_exp2f)
  return __builtin_amdgcn_exp2f(x);
#else
  return exp2f(x);
#endif
}

__device__ __forceinline__ bf16x8 ld16(const bf16* p) {
  return *reinterpret_cast<const bf16x8*>(p);
}

__device__ __forceinline__ unsigned packbf2(float a, float b) {
  union { bf16 h[2]; unsigned u; } v;
  v.h[0] = (bf16)a;
  v.h[1] = (bf16)b;
  return v.u;
}

__device__ __forceinline__ unsigned sx32(unsigned x) {
  return (unsigned)__shfl_xor((int)x, 32, 64);
}

// ---------------------------------------------------------------------------
// Kernel 0: cast fp32 -> bf16. Folds 1/sqrt(64) * log2(e) into the q-rows of
// W_qkv (softmax runs in the exp2 domain; v_exp_f32 IS 2^x).
// ---------------------------------------------------------------------------
__global__ __launch_bounds__(256) void cast_inputs(
    const float* __restrict__ x, const float* __restrict__ wqkv,
    const float* __restrict__ wout, bf16* __restrict__ xb,
    bf16* __restrict__ wqkvb, bf16* __restrict__ woutb) {
  const int NX = SEQ * HID;
  const int NW = 3 * HID * HID;
  const int NO = HID * HID;
  const int tot4 = (NX + NW + NO) >> 2;
  const float QSCALE = 0.125f * 1.44269504088896340736f;
  for (int i4 = blockIdx.x * blockDim.x + threadIdx.x; i4 < tot4;
       i4 += gridDim.x * blockDim.x) {
    const int i = i4 << 2;
    const float* src;
    bf16* dst;
    float scale = 1.0f;
    int off;
    if (i < NX) {
      src = x; dst = xb; off = i;
    } else if (i < NX + NW) {
      off = i - NX; src = wqkv; dst = wqkvb;
      if (off < HID * HID) scale = QSCALE;  // q-rows
    } else {
      off = i - NX - NW; src = wout; dst = woutb;
    }
    f32x4 v = *reinterpret_cast<const f32x4*>(src + off);
    bf16x4 o;
#pragma unroll
    for (int j = 0; j < 4; ++j) o[j] = (bf16)(v[j] * scale);
    *reinterpret_cast<bf16x4*>(dst + off) = o;
  }
}

// ---------------------------------------------------------------------------
// GEMM C[M,N] = A[M,K] * B[N,K]^T, bf16 in, fp32 accum. 128x128 tile, BK=64.
// EPI=0: fp32 row-major C.  EPI=1: scatter bf16 q[h][s][d] / k[h][s][d] /
// vt[h][d][s].
// ---------------------------------------------------------------------------
template <int EPI>
__global__ __launch_bounds__(256) void gemm_bt(
    const bf16* __restrict__ A, const bf16* __restrict__ B,
    float* __restrict__ C, bf16* __restrict__ Qo, bf16* __restrict__ Ko,
    bf16* __restrict__ VTo, int M, int N, int K) {
  __shared__ __align__(16) bf16 lds_a[128 * 64];
  __shared__ __align__(16) bf16 lds_b[128 * 64];
  const int tid = threadIdx.x;
  const int lane = tid & 63;
  const int wv = tid >> 6;
  const int wr = wv >> 1, wc = wv & 1;
  const int rsel = lane & 15, hi = lane >> 4;
  const int m0 = blockIdx.y * 128;
  const int n0 = blockIdx.x * 128;
  f32x4 acc[4][4] = {};
  const int nk = K >> 6;
  for (int kt = 0; kt < nk; ++kt) {
    const int k0 = kt << 6;
#pragma unroll
    for (int j = 0; j < 4; ++j) {
      const int cc = (wv * 4 + j) * 64;
      const int c = cc + lane;
      const int row = c >> 3, kc = (c & 7) << 3;
      async_copy16(A + (size_t)(m0 + row) * K + k0 + kc, lds_a + cc * 8);
      async_copy16(B + (size_t)(n0 + row) * K + k0 + kc, lds_b + cc * 8);
    }
    __syncthreads();
#pragma unroll
    for (int kk = 0; kk < 2; ++kk) {
      const int kof = kk * 32 + hi * 8;
      bf16x8 af[4], bfr[4];
#pragma unroll
      for (int mi = 0; mi < 4; ++mi)
        af[mi] = *reinterpret_cast<const bf16x8*>(
            &lds_a[(wr * 64 + mi * 16 + rsel) * 64 + kof]);
#pragma unroll
      for (int ni = 0; ni < 4; ++ni)
        bfr[ni] = *reinterpret_cast<const bf16x8*>(
            &lds_b[(wc * 64 + ni * 16 + rsel) * 64 + kof]);
#pragma unroll
      for (int mi = 0; mi < 4; ++mi)
#pragma unroll
        for (int ni = 0; ni < 4; ++ni)
          acc[mi][ni] = MFMA16(af[mi], bfr[ni], acc[mi][ni]);
    }
    __syncthreads();
  }
  if constexpr (EPI == 0) {
#pragma unroll
    for (int mi = 0; mi < 4; ++mi)
#pragma unroll
      for (int ni = 0; ni < 4; ++ni) {
        const int r0 = m0 + wr * 64 + mi * 16 + hi * 4;
        const int col = n0 + wc * 64 + ni * 16 + rsel;
#pragma unroll
        for (int i = 0; i < 4; ++i)
          C[(size_t)(r0 + i) * N + col] = acc[mi][ni][i];
      }
  } else {
#pragma unroll
    for (int mi = 0; mi < 4; ++mi)
#pragma unroll
      for (int ni = 0; ni < 4; ++ni) {
        const int r0 = m0 + wr * 64 + mi * 16 + hi * 4;
        const int n = n0 + wc * 64 + ni * 16 + rsel;
        const int qi = n >> 10;
        const int h = (n >> 6) & 15;
        const int d = n & 63;
#pragma unroll
        for (int i = 0; i < 4; ++i) {
          const bf16 val = (bf16)acc[mi][ni][i];
          const int s = r0 + i;
          if (qi == 0)
            Qo[((size_t)h * SEQ + s) * HDM + d] = val;
          else if (qi == 1)
            Ko[((size_t)h * SEQ + s) * HDM + d] = val;
          else
            VTo[((size_t)h * HDM + d) * SEQ + s] = val;
        }
      }
  }
}

// ---------------------------------------------------------------------------
// Flash attention fwd, LDS-free swapped-operand 32x32 structure.
// Grid (SEQ/128, NHD), 4 independent waves x 32 q-rows; no barriers, no LDS.
//
// QK^T: S^T = mfma(K, Q)  -> lane owns q = lane&31; its 32 t-values (of 64;
//   partner lane^32 holds the rest) sit in st[T][r], t = T*32+(r&3)+8*(r>>2)+4*h5.
// Softmax: lane-local + one shfl_xor(32); exp2 domain (scale folded into Q).
// PV: O^T = mfma(V^T, P^T) -> col q = lane&31 again, so rescale + 1/l are
//   lane-local. P^T B-frags built in-register via pack + half-swap.
// NOTE: all cross-half shuffles are UNCONDITIONAL straight-line calls (full
// exec mask); only the pure selects depend on the divergent h5. Putting a
// __shfl inside `h5 ? ... : ...` is divergent-execution UB (round-3 bug).
// ---------------------------------------------------------------------------
__global__ __launch_bounds__(256) void attn_fwd(
    const bf16* __restrict__ Q, const bf16* __restrict__ K,
    const bf16* __restrict__ VT, bf16* __restrict__ O) {
  const int tid = threadIdx.x, lane = tid & 63, wv = tid >> 6;
  const int q5 = lane & 31, h5 = lane >> 5;
  const int h = blockIdx.y;
  const int s0 = blockIdx.x * 128 + wv * 32;
  const bf16* qh = Q + (size_t)h * SEQ * HDM;
  const bf16* kh = K + (size_t)h * SEQ * HDM;
  const bf16* vh = VT + (size_t)h * HDM * SEQ;

  // Q B-fragments: col q = lane&31, k(d) = kk*16 + h5*8 + j. 16 VGPR, held.
  bf16x8 qf[4];
#pragma unroll
  for (int kk = 0; kk < 4; ++kk)
    qf[kk] = ld16(qh + (size_t)(s0 + q5) * HDM + kk * 16 + h5 * 8);

  bf16x8 kf[2][4];  // K A-frags: row t = T*32+q5, k(d) = kk*16+h5*8+j
  bf16x8 vf[4][2];  // V^T A-frags: row d = dt*32+q5, k(t) = kt*16+h5*8+j
#pragma unroll
  for (int T = 0; T < 2; ++T)
#pragma unroll
    for (int kk = 0; kk < 4; ++kk)
      kf[T][kk] = ld16(kh + (size_t)(T * 32 + q5) * HDM + kk * 16 + h5 * 8);
#pragma unroll
  for (int kt = 0; kt < 4; ++kt)
#pragma unroll
    for (int dt = 0; dt < 2; ++dt)
      vf[kt][dt] = ld16(vh + (size_t)(dt * 32 + q5) * SEQ + kt * 16 + h5 * 8);

  f32x16 o[2] = {};
  float mrow = -1e30f, lrow = 0.0f;

  for (int t0 = 0; t0 < SEQ; t0 += 64) {
    const int tn = (t0 + 64 < SEQ) ? t0 + 64 : 0;

    // ---- QK^T: st[T] = S^T tile [32 t][32 q]
    f32x16 st[2] = {};
#pragma unroll
    for (int kk = 0; kk < 4; ++kk)
#pragma unroll
      for (int T = 0; T < 2; ++T)
        st[T] = MFMA32(kf[T][kk], qf[kk], st[T]);

    // prefetch next K tile (covered by softmax+PV below)
#pragma unroll
    for (int T = 0; T < 2; ++T)
#pragma unroll
      for (int kk = 0; kk < 4; ++kk)
        kf[T][kk] =
            ld16(kh + (size_t)(tn + T * 32 + q5) * HDM + kk * 16 + h5 * 8);

    // ---- online softmax (lane-local row state; exp2 domain)
    float mx = st[0][0];
#pragma unroll
    for (int r = 1; r < 16; ++r) mx = fmaxf(mx, st[0][r]);
#pragma unroll
    for (int r = 0; r < 16; ++r) mx = fmaxf(mx, st[1][r]);
    mx = fmaxf(mx, __shfl_xor(mx, 32, 64));
    const float mnew = fmaxf(mrow, mx);
    const float scal = fexp2(mrow - mnew);
    float ps = 0.0f;
#pragma unroll
    for (int T = 0; T < 2; ++T)
#pragma unroll
      for (int r = 0; r < 16; ++r) {
        const float p = fexp2(st[T][r] - mnew);
        st[T][r] = p;
        ps += p;
      }
    ps += __shfl_xor(ps, 32, 64);
    lrow = lrow * scal + ps;
    mrow = mnew;
#pragma unroll
    for (int dt = 0; dt < 2; ++dt)
#pragma unroll
      for (int r = 0; r < 16; ++r) o[dt][r] *= scal;

    // ---- PV: build P^T B-frag per kt, accumulate O^T
#pragma unroll
    for (int kt = 0; kt < 4; ++kt) {
      const int T = kt >> 1, b = (kt & 1) * 8;
      const unsigned p00 = packbf2(st[T][b + 0], st[T][b + 1]);
      const unsigned p01 = packbf2(st[T][b + 2], st[T][b + 3]);
      const unsigned p10 = packbf2(st[T][b + 4], st[T][b + 5]);
      const unsigned p11 = packbf2(st[T][b + 6], st[T][b + 7]);
      // UNCONDITIONAL cross-half swaps (full exec), THEN pure selects.
      const unsigned x00 = sx32(p00);
      const unsigned x01 = sx32(p01);
      const unsigned x10 = sx32(p10);
      const unsigned x11 = sx32(p11);
      // dest elem j needs t_local = (kt&1)*16 + h5*8 + j
      union { unsigned u[4]; bf16x8 v; } pw;
      pw.u[0] = h5 ? x10 : p00;
      pw.u[1] = h5 ? x11 : p01;
      pw.u[2] = h5 ? p10 : x00;
      pw.u[3] = h5 ? p11 : x01;
#pragma unroll
      for (int dt = 0; dt < 2; ++dt)
        o[dt] = MFMA32(vf[kt][dt], pw.v, o[dt]);
    }

    // prefetch next V tile (covered by next QK^T + softmax)
#pragma unroll
    for (int kt = 0; kt < 4; ++kt)
#pragma unroll
      for (int dt = 0; dt < 2; ++dt)
        vf[kt][dt] =
            ld16(vh + (size_t)(dt * 32 + q5) * SEQ + tn + kt * 16 + h5 * 8);
  }

  // ---- epilogue: O[s0+q][h*64 + d'], d' = (r&3) + 8*(r>>2) + 4*h5 + 32*dt
  const float linv = 1.0f / lrow;
  bf16* op = O + (size_t)(s0 + q5) * HID + h * HDM;
#pragma unroll
  for (int dt = 0; dt < 2; ++dt)
#pragma unroll
    for (int rg = 0; rg < 4; ++rg) {
      bf16x4 w;
#pragma unroll
      for (int j = 0; j < 4; ++j) w[j] = (bf16)(o[dt][rg * 4 + j] * linv);
      *reinterpret_cast<bf16x4*>(op + dt * 32 + rg * 8 + h5 * 4) = w;
    }
}

// ---------------------------------------------------------------------------
// Workspace packing (40 MB; aob aliases xb, dead after QKV GEMM):
//   [ 0, 8)  xb / aob   [ 8,14) wqkvb   [14,16) woutb
//   [16,24)  qb         [24,32) kb      [32,40) vtb
// ---------------------------------------------------------------------------
extern "C" void kernel_launch(void* const* d_in, const int* in_sizes, int n_in,
                              void* d_out, int out_size, void* d_ws,
                              size_t ws_size, hipStream_t stream) {
  const float* x = (const float*)d_in[0];
  const float* wqkv = (const float*)d_in[1];
  const float* wout = (const float*)d_in[2];
  float* out = (float*)d_out;
  char* ws = (char*)d_ws;
  const size_t MB = 1024 * 1024;
  bf16* xb = (bf16*)(ws);
  bf16* wqkvb = (bf16*)(ws + 8 * MB);
  bf16* woutb = (bf16*)(ws + 14 * MB);
  bf16* qb = (bf16*)(ws + 16 * MB);
  bf16* kb = (bf16*)(ws + 24 * MB);
  bf16* vtb = (bf16*)(ws + 32 * MB);
  bf16* aob = (bf16*)(ws);  // aliases xb (dead by then)

  cast_inputs<<<2048, 256, 0, stream>>>(x, wqkv, wout, xb, wqkvb, woutb);
  gemm_bt<1><<<dim3(3 * HID / 128, SEQ / 128), 256, 0, stream>>>(
      xb, wqkvb, nullptr, qb, kb, vtb, SEQ, 3 * HID, HID);
  attn_fwd<<<dim3(SEQ / 128, NHD), 256, 0, stream>>>(qb, kb, vtb, aob);
  gemm_bt<0><<<dim3(HID / 128, SEQ / 128), 256, 0, stream>>>(
      aob, woutb, out, nullptr, nullptr, nullptr, SEQ, HID, HID);
}